// Round 2
// baseline (886.082 us; speedup 1.0000x reference)
//
#include <hip/hip_runtime.h>
#include <hip/hip_bf16.h>

#define B_    16384
#define S_    37
#define F_    17
#define OWN_  9
#define NOUT_ 23
#define OBS_ROW 646   // 38*17

typedef __bf16 bf16x8 __attribute__((ext_vector_type(8)));
typedef float  f32x4  __attribute__((ext_vector_type(4)));

#define MFMA(a,b,c) __builtin_amdgcn_mfma_f32_16x16x32_bf16(a, b, c, 0, 0, 0)

// ---- fragment-linear weight layout in ws (bf16 elements) ----
// dst[(k>>3)*(Np*8) + n*8 + (k&7)] = W[k][n]  (zero-padded)
#define W1F_OFF   0        // Np=256, Kp=32   -> 8192
#define W2F_OFF   8192     // Np=256, Kp=256  -> 65536
#define W3F_OFF   73728    // Np=128, Kp=256  -> 32768
#define AW1F_OFF  106496   // Np=256, Kp=160  -> 40960
#define AW2F_OFF  147456   // Np=256, Kp=256  -> 65536
#define AW3F_OFF  212992   // Np=32,  Kp=256  -> 8192
#define VW1F_OFF  221184   // Np=256, Kp=160  -> 40960
#define VW2F_OFF  262144   // Np=256, Kp=256  -> 65536
#define VW3F_OFF  327680   // Np=16,  Kp=256  -> 4096
#define PREP_TOTAL 331776

__global__ void prep_kernel(const float* __restrict__ sW1, const float* __restrict__ sW2,
                            const float* __restrict__ sW3, const float* __restrict__ aW1,
                            const float* __restrict__ aW2, const float* __restrict__ aW3,
                            const float* __restrict__ vW1, const float* __restrict__ vW2,
                            const float* __restrict__ vW3, __bf16* __restrict__ ws)
{
    int j = blockIdx.x * 256 + threadIdx.x;
    const float* src; __bf16* dst; int Np, Ks, Ns;
    if (j < 8192)                  { dst = ws + W1F_OFF;  src = sW1; Np = 256; Ks = 17;  Ns = 256; }
    else if ((j -= 8192)  < 65536) { dst = ws + W2F_OFF;  src = sW2; Np = 256; Ks = 256; Ns = 256; }
    else if ((j -= 65536) < 32768) { dst = ws + W3F_OFF;  src = sW3; Np = 128; Ks = 256; Ns = 128; }
    else if ((j -= 32768) < 40960) { dst = ws + AW1F_OFF; src = aW1; Np = 256; Ks = 137; Ns = 256; }
    else if ((j -= 40960) < 65536) { dst = ws + AW2F_OFF; src = aW2; Np = 256; Ks = 256; Ns = 256; }
    else if ((j -= 65536) < 8192)  { dst = ws + AW3F_OFF; src = aW3; Np = 32;  Ks = 256; Ns = 23;  }
    else if ((j -= 8192)  < 40960) { dst = ws + VW1F_OFF; src = vW1; Np = 256; Ks = 137; Ns = 256; }
    else if ((j -= 40960) < 65536) { dst = ws + VW2F_OFF; src = vW2; Np = 256; Ks = 256; Ns = 256; }
    else { j -= 65536;               dst = ws + VW3F_OFF; src = vW3; Np = 16;  Ks = 256; Ns = 1;   }
    const int c = j / (Np * 8), rem = j - c * Np * 8, n = rem >> 3, e = rem & 7, k = c * 8 + e;
    const float v = (k < Ks && n < Ns) ? src[k * Ns + n] : 0.f;
    dst[j] = (__bf16)v;
}

// One block = 16 batch rows. Seq loop: 19 iters x (16 b x 2 s) = 32-row MFMA
// tiles; 3 barriers/iter; obs prefetch hides under L1. Heads fused at the end
// (actor rows 0..15 / value rows 16..31 of the same act buffers).
__global__ __launch_bounds__(256, 4) void fused_kernel(
    const float* __restrict__ obs,
    const float* __restrict__ sb1, const float* __restrict__ sb2, const float* __restrict__ sb3,
    const float* __restrict__ ab1, const float* __restrict__ ab2, const float* __restrict__ ab3,
    const float* __restrict__ vb1, const float* __restrict__ vb2, const float* __restrict__ vb3,
    const __bf16* __restrict__ ws, float* __restrict__ out)
{
    __shared__ __align__(16) char pool[37888];
    __bf16* act1 = (__bf16*)pool;                    // [32 kch][32 row][8]
    __bf16* act2 = (__bf16*)(pool + 16384);          // [32 kch][32 row][8]
    __bf16* xs0  = (__bf16*)(pool + 32768);          // [4 kch][32 row][8]
    __bf16* xs1  = (__bf16*)(pool + 34816);
    float*  sm0  = (float*)(pool + 36864);
    float*  sm1  = (float*)(pool + 36992);
    __bf16* catf = (__bf16*)(pool + 32768);          // [20 kch][16 row][8] (aliases xs/sm)

    const __bf16* W1f  = ws + W1F_OFF;
    const __bf16* W2f  = ws + W2F_OFF;
    const __bf16* W3f  = ws + W3F_OFF;
    const __bf16* AW1f = ws + AW1F_OFF;
    const __bf16* AW2f = ws + AW2F_OFF;
    const __bf16* AW3f = ws + AW3F_OFF;
    const __bf16* VW1f = ws + VW1F_OFF;
    const __bf16* VW2f = ws + VW2F_OFF;
    const __bf16* VW3f = ws + VW3F_OFF;

    const int tid  = threadIdx.x;
    const int wave = tid >> 6;
    const int lane = tid & 63;
    const int q    = lane >> 4;
    const int l16  = lane & 15;
    const int n64  = wave * 64 + l16;
    const int b0   = blockIdx.x * 16;
    const f32x4 z4 = {0.f, 0.f, 0.f, 0.f};

    // zero both Xs buffers (chunks 2,3 stay zero forever: elems 17..31 pad)
    for (int i = tid; i < 2048; i += 256) xs0[i] = (__bf16)0.f;

    // hoist W1 B-frags + biases (loop-invariant)
    bf16x8 w1f[4]; float b1v[4], b2v[4], b3v[2];
    #pragma unroll
    for (int nt = 0; nt < 4; ++nt) {
        const int n = n64 + nt * 16;
        w1f[nt] = *(const bf16x8*)(W1f + ((size_t)q * 256 + n) * 8);
        b1v[nt] = sb1[n];
        b2v[nt] = sb2[n];
    }
    b3v[0] = sb3[wave * 32 + l16];
    b3v[1] = sb3[wave * 32 + 16 + l16];

    const int  lrow = wave * 8 + lane;   // loader row, valid when lane<8
    const bool isld = (lane < 8);

    __syncthreads();  // zeros visible before preload stores

    // preload iter 0 (s = lrow>>4)
    if (isld) {
        const float* p = obs + (size_t)(b0 + (lrow & 15)) * OBS_ROW + ((lrow >> 4) + 1) * F_;
        float sm = 0.f;
        #pragma unroll
        for (int c = 0; c < F_; ++c) {
            const float v = p[c];
            sm += fabsf(v);
            xs0[((c >> 3) * 32 + lrow) * 8 + (c & 7)] = (__bf16)v;
        }
        sm0[lrow] = sm;
    }

    f32x4 vsum[2][2];
    #pragma unroll
    for (int nt = 0; nt < 2; ++nt) { vsum[nt][0] = z4; vsum[nt][1] = z4; }

    for (int it = 0; it < 19; ++it) {
        __bf16* xc  = (it & 1) ? xs1 : xs0;
        __bf16* xn  = (it & 1) ? xs0 : xs1;
        float*  smc = (it & 1) ? sm1 : sm0;
        float*  smn = (it & 1) ? sm0 : sm1;

        __syncthreads();  // B_a: Xs[cur]/smask[cur] ready; act1,act2 free

        // issue prefetch loads for it+1 (registers only; consumed after L1)
        float pf[F_]; bool pvalid = false;
        if (it < 18 && isld) {
            const int s = 2 * (it + 1) + (lrow >> 4);
            pvalid = (s < S_);
            if (pvalid) {
                const float* p = obs + (size_t)(b0 + (lrow & 15)) * OBS_ROW + (s + 1) * F_;
                #pragma unroll
                for (int c = 0; c < F_; ++c) pf[c] = p[c];
            }
        }

        // ---- layer 1: (32,32) x (32,256) -> act1 ----
        {
            const bf16x8 af0 = *(const bf16x8*)(xc + (q * 32 + l16) * 8);
            const bf16x8 af1 = *(const bf16x8*)(xc + (q * 32 + 16 + l16) * 8);
            #pragma unroll
            for (int nt = 0; nt < 4; ++nt) {
                const f32x4 h0 = MFMA(af0, w1f[nt], z4);
                const f32x4 h1 = MFMA(af1, w1f[nt], z4);
                const int n = n64 + nt * 16, c = n >> 3, e = n & 7;
                #pragma unroll
                for (int r = 0; r < 4; ++r) {
                    float v0 = h0[r] + b1v[nt]; v0 = v0 > 0.f ? v0 : 0.f;
                    float v1 = h1[r] + b1v[nt]; v1 = v1 > 0.f ? v1 : 0.f;
                    act1[(c * 32 + q * 4 + r) * 8 + e]      = (__bf16)v0;
                    act1[(c * 32 + 16 + q * 4 + r) * 8 + e] = (__bf16)v1;
                }
            }
        }

        // drain prefetch -> Xs[nxt]
        if (it < 18 && isld) {
            float sm = 0.f;
            if (pvalid) {
                #pragma unroll
                for (int c = 0; c < F_; ++c) {
                    sm += fabsf(pf[c]);
                    xn[((c >> 3) * 32 + lrow) * 8 + (c & 7)] = (__bf16)pf[c];
                }
            }
            smn[lrow] = pvalid ? sm : 0.f;
        }

        __syncthreads();  // B_b: act1 ready

        // ---- layer 2: (32,256) x (256,256) -> act2 ----
        {
            f32x4 h2[4][2];
            #pragma unroll
            for (int nt = 0; nt < 4; ++nt) { h2[nt][0] = z4; h2[nt][1] = z4; }
            #pragma unroll
            for (int k = 0; k < 8; ++k) {
                const int k8 = k * 4 + q;
                const bf16x8 a0 = *(const bf16x8*)(act1 + (k8 * 32 + l16) * 8);
                const bf16x8 a1 = *(const bf16x8*)(act1 + (k8 * 32 + 16 + l16) * 8);
                #pragma unroll
                for (int nt = 0; nt < 4; ++nt) {
                    const bf16x8 bf = *(const bf16x8*)(W2f + ((size_t)k8 * 256 + n64 + nt * 16) * 8);
                    h2[nt][0] = MFMA(a0, bf, h2[nt][0]);
                    h2[nt][1] = MFMA(a1, bf, h2[nt][1]);
                }
            }
            #pragma unroll
            for (int nt = 0; nt < 4; ++nt) {
                const int n = n64 + nt * 16, c = n >> 3, e = n & 7;
                #pragma unroll
                for (int r = 0; r < 4; ++r) {
                    float v0 = h2[nt][0][r] + b2v[nt]; v0 = v0 > 0.f ? v0 : 0.f;
                    float v1 = h2[nt][1][r] + b2v[nt]; v1 = v1 > 0.f ? v1 : 0.f;
                    act2[(c * 32 + q * 4 + r) * 8 + e]      = (__bf16)v0;
                    act2[(c * 32 + 16 + q * 4 + r) * 8 + e] = (__bf16)v1;
                }
            }
        }
        __syncthreads();  // B_c: act2 ready

        // ---- layer 3: (32,256) x (256,128), mask, accumulate ----
        {
            f32x4 h3[2][2];
            #pragma unroll
            for (int nt = 0; nt < 2; ++nt) { h3[nt][0] = z4; h3[nt][1] = z4; }
            #pragma unroll
            for (int k = 0; k < 8; ++k) {
                const int k8 = k * 4 + q;
                const bf16x8 a0 = *(const bf16x8*)(act2 + (k8 * 32 + l16) * 8);
                const bf16x8 a1 = *(const bf16x8*)(act2 + (k8 * 32 + 16 + l16) * 8);
                #pragma unroll
                for (int nt = 0; nt < 2; ++nt) {
                    const bf16x8 bf = *(const bf16x8*)(W3f + ((size_t)k8 * 128 + wave * 32 + nt * 16 + l16) * 8);
                    h3[nt][0] = MFMA(a0, bf, h3[nt][0]);
                    h3[nt][1] = MFMA(a1, bf, h3[nt][1]);
                }
            }
            #pragma unroll
            for (int nt = 0; nt < 2; ++nt)
                #pragma unroll
                for (int m = 0; m < 2; ++m)
                    #pragma unroll
                    for (int r = 0; r < 4; ++r) {
                        const float mv = smc[m * 16 + q * 4 + r];
                        float v = h3[nt][m][r] + b3v[nt];
                        v = v > 0.f ? v : 0.f;
                        vsum[nt][m][r] += (mv != 0.f) ? v : 0.f;
                    }
        }
    }

    __syncthreads();  // seq loop done; xs/sm regions dead -> catf writable

    // ---- stage cat (frag-major, 16 rows x 20 chunks) ----
    if (tid < 16) {
        const float* p = obs + (size_t)(b0 + tid) * OBS_ROW;  // s_own
        #pragma unroll
        for (int c = 0; c < 8; ++c) catf[(16 * 16 + tid) * 8 + c] = (__bf16)p[c];
        catf[(17 * 16 + tid) * 8 + 0] = (__bf16)p[8];
        #pragma unroll
        for (int c = 1; c < 8; ++c) catf[(17 * 16 + tid) * 8 + c] = (__bf16)0.f;
    } else if (tid < 32) {
        const int rr = tid - 16;
        #pragma unroll
        for (int c = 0; c < 8; ++c) {
            catf[(18 * 16 + rr) * 8 + c] = (__bf16)0.f;
            catf[(19 * 16 + rr) * 8 + c] = (__bf16)0.f;
        }
    }
    #pragma unroll
    for (int nt = 0; nt < 2; ++nt) {
        const int col = wave * 32 + nt * 16 + l16, c = col >> 3, e = col & 7;
        #pragma unroll
        for (int r = 0; r < 4; ++r) {
            const float v = vsum[nt][0][r] + vsum[nt][1][r];
            catf[(c * 16 + q * 4 + r) * 8 + e] = (__bf16)v;
        }
    }
    __syncthreads();  // catf ready

    // ---- head layer 1: (16,160) x (160,256) x 2 heads -> act1 ----
    {
        f32x4 ha[4], hv[4];
        #pragma unroll
        for (int nt = 0; nt < 4; ++nt) { ha[nt] = z4; hv[nt] = z4; }
        #pragma unroll
        for (int k = 0; k < 5; ++k) {
            const int k8 = k * 4 + q;
            const bf16x8 ca = *(const bf16x8*)(catf + (k8 * 16 + l16) * 8);
            #pragma unroll
            for (int nt = 0; nt < 4; ++nt) {
                const int n = n64 + nt * 16;
                const bf16x8 ba = *(const bf16x8*)(AW1f + ((size_t)k8 * 256 + n) * 8);
                const bf16x8 bv = *(const bf16x8*)(VW1f + ((size_t)k8 * 256 + n) * 8);
                ha[nt] = MFMA(ca, ba, ha[nt]);
                hv[nt] = MFMA(ca, bv, hv[nt]);
            }
        }
        #pragma unroll
        for (int nt = 0; nt < 4; ++nt) {
            const int n = n64 + nt * 16, c = n >> 3, e = n & 7;
            const float ba_ = ab1[n], bv_ = vb1[n];
            #pragma unroll
            for (int r = 0; r < 4; ++r) {
                float va = ha[nt][r] + ba_; va = va > 0.f ? va : 0.f;
                float vv = hv[nt][r] + bv_; vv = vv > 0.f ? vv : 0.f;
                act1[(c * 32 + q * 4 + r) * 8 + e]      = (__bf16)va;   // actor rows 0..15
                act1[(c * 32 + 16 + q * 4 + r) * 8 + e] = (__bf16)vv;   // value rows 16..31
            }
        }
    }
    __syncthreads();

    // ---- head layer 2: (16,256) x (256,256) x 2 heads -> act2 ----
    {
        f32x4 ha[4], hv[4];
        #pragma unroll
        for (int nt = 0; nt < 4; ++nt) { ha[nt] = z4; hv[nt] = z4; }
        #pragma unroll
        for (int k = 0; k < 8; ++k) {
            const int k8 = k * 4 + q;
            const bf16x8 a0 = *(const bf16x8*)(act1 + (k8 * 32 + l16) * 8);
            const bf16x8 a1 = *(const bf16x8*)(act1 + (k8 * 32 + 16 + l16) * 8);
            #pragma unroll
            for (int nt = 0; nt < 4; ++nt) {
                const int n = n64 + nt * 16;
                const bf16x8 ba = *(const bf16x8*)(AW2f + ((size_t)k8 * 256 + n) * 8);
                const bf16x8 bv = *(const bf16x8*)(VW2f + ((size_t)k8 * 256 + n) * 8);
                ha[nt] = MFMA(a0, ba, ha[nt]);
                hv[nt] = MFMA(a1, bv, hv[nt]);
            }
        }
        #pragma unroll
        for (int nt = 0; nt < 4; ++nt) {
            const int n = n64 + nt * 16, c = n >> 3, e = n & 7;
            const float ba_ = ab2[n], bv_ = vb2[n];
            #pragma unroll
            for (int r = 0; r < 4; ++r) {
                float va = ha[nt][r] + ba_; va = va > 0.f ? va : 0.f;
                float vv = hv[nt][r] + bv_; vv = vv > 0.f ? vv : 0.f;
                act2[(c * 32 + q * 4 + r) * 8 + e]      = (__bf16)va;
                act2[(c * 32 + 16 + q * 4 + r) * 8 + e] = (__bf16)vv;
            }
        }
    }
    __syncthreads();

    // ---- head layer 3 ----
    if (wave < 2) {       // actor logits, cols wave*16 + l16
        f32x4 acc = z4;
        #pragma unroll
        for (int k = 0; k < 8; ++k) {
            const int k8 = k * 4 + q;
            const bf16x8 a0 = *(const bf16x8*)(act2 + (k8 * 32 + l16) * 8);
            const bf16x8 bf = *(const bf16x8*)(AW3f + ((size_t)k8 * 32 + wave * 16 + l16) * 8);
            acc = MFMA(a0, bf, acc);
        }
        const int col = wave * 16 + l16;
        if (col < NOUT_) {
            const float bb = ab3[col];
            #pragma unroll
            for (int r = 0; r < 4; ++r)
                out[(size_t)(b0 + q * 4 + r) * NOUT_ + col] = acc[r] + bb;
        }
    } else if (wave == 2) {  // value
        f32x4 acc = z4;
        #pragma unroll
        for (int k = 0; k < 8; ++k) {
            const int k8 = k * 4 + q;
            const bf16x8 a1 = *(const bf16x8*)(act2 + (k8 * 32 + 16 + l16) * 8);
            const bf16x8 bf = *(const bf16x8*)(VW3f + ((size_t)k8 * 16 + l16) * 8);
            acc = MFMA(a1, bf, acc);
        }
        if (l16 == 0) {
            const float bb = vb3[0];
            #pragma unroll
            for (int r = 0; r < 4; ++r)
                out[(size_t)B_ * NOUT_ + b0 + q * 4 + r] = acc[r] + bb;
        }
    }
}

extern "C" void kernel_launch(void* const* d_in, const int* in_sizes, int n_in,
                              void* d_out, int out_size, void* d_ws, size_t ws_size,
                              hipStream_t stream)
{
    const float* obs = (const float*)d_in[0];
    const float* sW1 = (const float*)d_in[1];
    const float* sb1 = (const float*)d_in[2];
    const float* sW2 = (const float*)d_in[3];
    const float* sb2 = (const float*)d_in[4];
    const float* sW3 = (const float*)d_in[5];
    const float* sb3 = (const float*)d_in[6];
    const float* aW1 = (const float*)d_in[7];
    const float* ab1 = (const float*)d_in[8];
    const float* aW2 = (const float*)d_in[9];
    const float* ab2 = (const float*)d_in[10];
    const float* aW3 = (const float*)d_in[11];
    const float* ab3 = (const float*)d_in[12];
    const float* vW1 = (const float*)d_in[13];
    const float* vb1 = (const float*)d_in[14];
    const float* vW2 = (const float*)d_in[15];
    const float* vb2 = (const float*)d_in[16];
    const float* vW3 = (const float*)d_in[17];
    const float* vb3 = (const float*)d_in[18];

    __bf16* ws = (__bf16*)d_ws;
    float* out = (float*)d_out;

    hipLaunchKernelGGL(prep_kernel, dim3(PREP_TOTAL / 256), dim3(256), 0, stream,
                       sW1, sW2, sW3, aW1, aW2, aW3, vW1, vW2, vW3, ws);
    hipLaunchKernelGGL(fused_kernel, dim3(B_ / 16), dim3(256), 0, stream,
                       obs, sb1, sb2, sb3, ab1, ab2, ab3, vb1, vb2, vb3,
                       (const __bf16*)ws, out);
}

// Round 3
// 739.571 us; speedup vs baseline: 1.1981x; 1.1981x over previous
//
#include <hip/hip_runtime.h>
#include <hip/hip_bf16.h>

#define B_    16384
#define S_    37
#define F_    17
#define OWN_  9
#define NOUT_ 23
#define OBS_ROW 646   // 38*17

typedef __bf16 bf16x8 __attribute__((ext_vector_type(8)));
typedef float  f32x4  __attribute__((ext_vector_type(4)));

#define MFMA(a,b,c) __builtin_amdgcn_mfma_f32_16x16x32_bf16(a, b, c, 0, 0, 0)

// ---- fragment-linear weight layout in ws (bf16 elements) ----
// dst[(k>>3)*(Np*8) + n*8 + (k&7)] = W[k][n]  (zero-padded)
#define W1F_OFF   0        // Np=256, Kp=32   -> 8192
#define W2F_OFF   8192     // Np=256, Kp=256  -> 65536
#define W3F_OFF   73728    // Np=128, Kp=256  -> 32768
#define AW1F_OFF  106496   // Np=256, Kp=160  -> 40960
#define AW2F_OFF  147456   // Np=256, Kp=256  -> 65536
#define AW3F_OFF  212992   // Np=32,  Kp=256  -> 8192
#define VW1F_OFF  221184   // Np=256, Kp=160  -> 40960
#define VW2F_OFF  262144   // Np=256, Kp=256  -> 65536
#define VW3F_OFF  327680   // Np=16,  Kp=256  -> 4096
#define PREP_TOTAL 331776

__global__ void prep_kernel(const float* __restrict__ sW1, const float* __restrict__ sW2,
                            const float* __restrict__ sW3, const float* __restrict__ aW1,
                            const float* __restrict__ aW2, const float* __restrict__ aW3,
                            const float* __restrict__ vW1, const float* __restrict__ vW2,
                            const float* __restrict__ vW3, __bf16* __restrict__ ws)
{
    int j = blockIdx.x * 256 + threadIdx.x;
    const float* src; __bf16* dst; int Np, Ks, Ns;
    if (j < 8192)                  { dst = ws + W1F_OFF;  src = sW1; Np = 256; Ks = 17;  Ns = 256; }
    else if ((j -= 8192)  < 65536) { dst = ws + W2F_OFF;  src = sW2; Np = 256; Ks = 256; Ns = 256; }
    else if ((j -= 65536) < 32768) { dst = ws + W3F_OFF;  src = sW3; Np = 128; Ks = 256; Ns = 128; }
    else if ((j -= 32768) < 40960) { dst = ws + AW1F_OFF; src = aW1; Np = 256; Ks = 137; Ns = 256; }
    else if ((j -= 40960) < 65536) { dst = ws + AW2F_OFF; src = aW2; Np = 256; Ks = 256; Ns = 256; }
    else if ((j -= 65536) < 8192)  { dst = ws + AW3F_OFF; src = aW3; Np = 32;  Ks = 256; Ns = 23;  }
    else if ((j -= 8192)  < 40960) { dst = ws + VW1F_OFF; src = vW1; Np = 256; Ks = 137; Ns = 256; }
    else if ((j -= 40960) < 65536) { dst = ws + VW2F_OFF; src = vW2; Np = 256; Ks = 256; Ns = 256; }
    else { j -= 65536;               dst = ws + VW3F_OFF; src = vW3; Np = 16;  Ks = 256; Ns = 1;   }
    const int c = j / (Np * 8), rem = j - c * Np * 8, n = rem >> 3, e = rem & 7, k = c * 8 + e;
    const float v = (k < Ks && n < Ns) ? src[k * Ns + n] : 0.f;
    dst[j] = (__bf16)v;
}

// One block = 16 batch rows. Seq loop: 19 iters x (16 b x 2 s) = 32-row MFMA
// tiles; 3 barriers/iter. Wave 3 streams obs for iter+1 into the alternate Xs
// buffer while waves 0-2 run layer 1. Heads fused at the end (actor rows
// 0..15 / value rows 16..31). launch_bounds(256,3): 170-VGPR cap -> NO spills
// (round 2's (256,4) cap caused 378 MB of scratch traffic + L2 thrash).
__global__ __launch_bounds__(256, 3) void fused_kernel(
    const float* __restrict__ obs,
    const float* __restrict__ sb1, const float* __restrict__ sb2, const float* __restrict__ sb3,
    const float* __restrict__ ab1, const float* __restrict__ ab2, const float* __restrict__ ab3,
    const float* __restrict__ vb1, const float* __restrict__ vb2, const float* __restrict__ vb3,
    const __bf16* __restrict__ ws, float* __restrict__ out)
{
    __shared__ __align__(16) char pool[37888];
    __bf16* act1 = (__bf16*)pool;                    // [32 kch][32 row][8]
    __bf16* act2 = (__bf16*)(pool + 16384);          // [32 kch][32 row][8]
    __bf16* xs0  = (__bf16*)(pool + 32768);          // [4 kch][32 row][8]
    __bf16* xs1  = (__bf16*)(pool + 34816);
    float*  sm0  = (float*)(pool + 36864);
    float*  sm1  = (float*)(pool + 36992);
    __bf16* catf = (__bf16*)(pool + 32768);          // [20 kch][16 row][8] (aliases xs/sm)

    const __bf16* W1f  = ws + W1F_OFF;
    const __bf16* W2f  = ws + W2F_OFF;
    const __bf16* W3f  = ws + W3F_OFF;
    const __bf16* AW1f = ws + AW1F_OFF;
    const __bf16* AW2f = ws + AW2F_OFF;
    const __bf16* AW3f = ws + AW3F_OFF;
    const __bf16* VW1f = ws + VW1F_OFF;
    const __bf16* VW2f = ws + VW2F_OFF;
    const __bf16* VW3f = ws + VW3F_OFF;

    const int tid  = threadIdx.x;
    const int wave = tid >> 6;
    const int lane = tid & 63;
    const int q    = lane >> 4;
    const int l16  = lane & 15;
    const int n64  = wave * 64 + l16;
    const int b0   = blockIdx.x * 16;
    const f32x4 z4 = {0.f, 0.f, 0.f, 0.f};

    // zero both Xs buffers (pad chunks stay zero forever)
    for (int i = tid; i < 2048; i += 256) xs0[i] = (__bf16)0.f;

    // hoist W1 B-frags + biases (loop-invariant)
    bf16x8 w1f[4]; float b1v[4], b2v[4], b3v[2];
    #pragma unroll
    for (int nt = 0; nt < 4; ++nt) {
        const int n = n64 + nt * 16;
        w1f[nt] = *(const bf16x8*)(W1f + ((size_t)q * 256 + n) * 8);
        b1v[nt] = sb1[n];
        b2v[nt] = sb2[n];
    }
    b3v[0] = sb3[wave * 32 + l16];
    b3v[1] = sb3[wave * 32 + 16 + l16];

    const bool loader = (wave == 3) && (lane < 32);

    __syncthreads();  // zeros visible before preload stores

    // preload iter 0: rows (b = b0+lane&15, s = lane>>4)
    if (loader) {
        const float* p = obs + (size_t)(b0 + (lane & 15)) * OBS_ROW + ((lane >> 4) + 1) * F_;
        float sm = 0.f;
        #pragma unroll
        for (int c = 0; c < F_; ++c) {
            const float v = p[c];
            sm += fabsf(v);
            xs0[((c >> 3) * 32 + lane) * 8 + (c & 7)] = (__bf16)v;
        }
        sm0[lane] = sm;
    }

    f32x4 vsum[2][2];
    #pragma unroll
    for (int nt = 0; nt < 2; ++nt) { vsum[nt][0] = z4; vsum[nt][1] = z4; }

    for (int it = 0; it < 19; ++it) {
        __bf16* xc  = (it & 1) ? xs1 : xs0;
        __bf16* xn  = (it & 1) ? xs0 : xs1;
        float*  smc = (it & 1) ? sm1 : sm0;
        float*  smn = (it & 1) ? sm0 : sm1;

        __syncthreads();  // B_a: Xs[cur]/smask[cur] ready; act1,act2 free

        // wave 3: load obs for it+1 straight into Xs[nxt] (short live range,
        // no registers held across MFMA sections -> no spill pressure)
        if (it < 18 && loader) {
            const int s = 2 * (it + 1) + (lane >> 4);
            if (s < S_) {
                const float* p = obs + (size_t)(b0 + (lane & 15)) * OBS_ROW + (s + 1) * F_;
                float sm = 0.f;
                #pragma unroll
                for (int c = 0; c < F_; ++c) {
                    const float v = p[c];
                    sm += fabsf(v);
                    xn[((c >> 3) * 32 + lane) * 8 + (c & 7)] = (__bf16)v;
                }
                smn[lane] = sm;
            } else {
                smn[lane] = 0.f;  // stale Xs row gets masked out
            }
        }

        // ---- layer 1: (32,32) x (32,256) -> act1 ----
        {
            const bf16x8 af0 = *(const bf16x8*)(xc + (q * 32 + l16) * 8);
            const bf16x8 af1 = *(const bf16x8*)(xc + (q * 32 + 16 + l16) * 8);
            #pragma unroll
            for (int nt = 0; nt < 4; ++nt) {
                const f32x4 h0 = MFMA(af0, w1f[nt], z4);
                const f32x4 h1 = MFMA(af1, w1f[nt], z4);
                const int n = n64 + nt * 16, c = n >> 3, e = n & 7;
                #pragma unroll
                for (int r = 0; r < 4; ++r) {
                    float v0 = h0[r] + b1v[nt]; v0 = v0 > 0.f ? v0 : 0.f;
                    float v1 = h1[r] + b1v[nt]; v1 = v1 > 0.f ? v1 : 0.f;
                    act1[(c * 32 + q * 4 + r) * 8 + e]      = (__bf16)v0;
                    act1[(c * 32 + 16 + q * 4 + r) * 8 + e] = (__bf16)v1;
                }
            }
        }
        __syncthreads();  // B_b: act1 ready

        // ---- layer 2: (32,256) x (256,256) -> act2 ----
        {
            f32x4 h2[4][2];
            #pragma unroll
            for (int nt = 0; nt < 4; ++nt) { h2[nt][0] = z4; h2[nt][1] = z4; }
            #pragma unroll
            for (int k = 0; k < 8; ++k) {
                const int k8 = k * 4 + q;
                const bf16x8 a0 = *(const bf16x8*)(act1 + (k8 * 32 + l16) * 8);
                const bf16x8 a1 = *(const bf16x8*)(act1 + (k8 * 32 + 16 + l16) * 8);
                #pragma unroll
                for (int nt = 0; nt < 4; ++nt) {
                    const bf16x8 bf = *(const bf16x8*)(W2f + ((size_t)k8 * 256 + n64 + nt * 16) * 8);
                    h2[nt][0] = MFMA(a0, bf, h2[nt][0]);
                    h2[nt][1] = MFMA(a1, bf, h2[nt][1]);
                }
            }
            #pragma unroll
            for (int nt = 0; nt < 4; ++nt) {
                const int n = n64 + nt * 16, c = n >> 3, e = n & 7;
                #pragma unroll
                for (int r = 0; r < 4; ++r) {
                    float v0 = h2[nt][0][r] + b2v[nt]; v0 = v0 > 0.f ? v0 : 0.f;
                    float v1 = h2[nt][1][r] + b2v[nt]; v1 = v1 > 0.f ? v1 : 0.f;
                    act2[(c * 32 + q * 4 + r) * 8 + e]      = (__bf16)v0;
                    act2[(c * 32 + 16 + q * 4 + r) * 8 + e] = (__bf16)v1;
                }
            }
        }
        __syncthreads();  // B_c: act2 ready

        // ---- layer 3: (32,256) x (256,128), mask, accumulate ----
        {
            f32x4 h3[2][2];
            #pragma unroll
            for (int nt = 0; nt < 2; ++nt) { h3[nt][0] = z4; h3[nt][1] = z4; }
            #pragma unroll
            for (int k = 0; k < 8; ++k) {
                const int k8 = k * 4 + q;
                const bf16x8 a0 = *(const bf16x8*)(act2 + (k8 * 32 + l16) * 8);
                const bf16x8 a1 = *(const bf16x8*)(act2 + (k8 * 32 + 16 + l16) * 8);
                #pragma unroll
                for (int nt = 0; nt < 2; ++nt) {
                    const bf16x8 bf = *(const bf16x8*)(W3f + ((size_t)k8 * 128 + wave * 32 + nt * 16 + l16) * 8);
                    h3[nt][0] = MFMA(a0, bf, h3[nt][0]);
                    h3[nt][1] = MFMA(a1, bf, h3[nt][1]);
                }
            }
            #pragma unroll
            for (int nt = 0; nt < 2; ++nt)
                #pragma unroll
                for (int m = 0; m < 2; ++m)
                    #pragma unroll
                    for (int r = 0; r < 4; ++r) {
                        const float mv = smc[m * 16 + q * 4 + r];
                        float v = h3[nt][m][r] + b3v[nt];
                        v = v > 0.f ? v : 0.f;
                        vsum[nt][m][r] += (mv != 0.f) ? v : 0.f;
                    }
        }
    }

    __syncthreads();  // seq loop done; xs/sm regions dead -> catf writable

    // ---- stage cat (frag-major, 16 rows x 20 chunks) ----
    if (tid < 16) {
        const float* p = obs + (size_t)(b0 + tid) * OBS_ROW;  // s_own
        #pragma unroll
        for (int c = 0; c < 8; ++c) catf[(16 * 16 + tid) * 8 + c] = (__bf16)p[c];
        catf[(17 * 16 + tid) * 8 + 0] = (__bf16)p[8];
        #pragma unroll
        for (int c = 1; c < 8; ++c) catf[(17 * 16 + tid) * 8 + c] = (__bf16)0.f;
    } else if (tid < 32) {
        const int rr = tid - 16;
        #pragma unroll
        for (int c = 0; c < 8; ++c) {
            catf[(18 * 16 + rr) * 8 + c] = (__bf16)0.f;
            catf[(19 * 16 + rr) * 8 + c] = (__bf16)0.f;
        }
    }
    #pragma unroll
    for (int nt = 0; nt < 2; ++nt) {
        const int col = wave * 32 + nt * 16 + l16, c = col >> 3, e = col & 7;
        #pragma unroll
        for (int r = 0; r < 4; ++r) {
            const float v = vsum[nt][0][r] + vsum[nt][1][r];
            catf[(c * 16 + q * 4 + r) * 8 + e] = (__bf16)v;
        }
    }
    __syncthreads();  // catf ready

    // ---- head layer 1: (16,160) x (160,256) x 2 heads -> act1 ----
    {
        f32x4 ha[4], hv[4];
        #pragma unroll
        for (int nt = 0; nt < 4; ++nt) { ha[nt] = z4; hv[nt] = z4; }
        #pragma unroll
        for (int k = 0; k < 5; ++k) {
            const int k8 = k * 4 + q;
            const bf16x8 ca = *(const bf16x8*)(catf + (k8 * 16 + l16) * 8);
            #pragma unroll
            for (int nt = 0; nt < 4; ++nt) {
                const int n = n64 + nt * 16;
                const bf16x8 ba = *(const bf16x8*)(AW1f + ((size_t)k8 * 256 + n) * 8);
                const bf16x8 bv = *(const bf16x8*)(VW1f + ((size_t)k8 * 256 + n) * 8);
                ha[nt] = MFMA(ca, ba, ha[nt]);
                hv[nt] = MFMA(ca, bv, hv[nt]);
            }
        }
        #pragma unroll
        for (int nt = 0; nt < 4; ++nt) {
            const int n = n64 + nt * 16, c = n >> 3, e = n & 7;
            const float ba_ = ab1[n], bv_ = vb1[n];
            #pragma unroll
            for (int r = 0; r < 4; ++r) {
                float va = ha[nt][r] + ba_; va = va > 0.f ? va : 0.f;
                float vv = hv[nt][r] + bv_; vv = vv > 0.f ? vv : 0.f;
                act1[(c * 32 + q * 4 + r) * 8 + e]      = (__bf16)va;   // actor rows 0..15
                act1[(c * 32 + 16 + q * 4 + r) * 8 + e] = (__bf16)vv;   // value rows 16..31
            }
        }
    }
    __syncthreads();

    // ---- head layer 2: (16,256) x (256,256) x 2 heads -> act2 ----
    {
        f32x4 ha[4], hv[4];
        #pragma unroll
        for (int nt = 0; nt < 4; ++nt) { ha[nt] = z4; hv[nt] = z4; }
        #pragma unroll
        for (int k = 0; k < 8; ++k) {
            const int k8 = k * 4 + q;
            const bf16x8 a0 = *(const bf16x8*)(act1 + (k8 * 32 + l16) * 8);
            const bf16x8 a1 = *(const bf16x8*)(act1 + (k8 * 32 + 16 + l16) * 8);
            #pragma unroll
            for (int nt = 0; nt < 4; ++nt) {
                const int n = n64 + nt * 16;
                const bf16x8 ba = *(const bf16x8*)(AW2f + ((size_t)k8 * 256 + n) * 8);
                const bf16x8 bv = *(const bf16x8*)(VW2f + ((size_t)k8 * 256 + n) * 8);
                ha[nt] = MFMA(a0, ba, ha[nt]);
                hv[nt] = MFMA(a1, bv, hv[nt]);
            }
        }
        #pragma unroll
        for (int nt = 0; nt < 4; ++nt) {
            const int n = n64 + nt * 16, c = n >> 3, e = n & 7;
            const float ba_ = ab2[n], bv_ = vb2[n];
            #pragma unroll
            for (int r = 0; r < 4; ++r) {
                float va = ha[nt][r] + ba_; va = va > 0.f ? va : 0.f;
                float vv = hv[nt][r] + bv_; vv = vv > 0.f ? vv : 0.f;
                act2[(c * 32 + q * 4 + r) * 8 + e]      = (__bf16)va;
                act2[(c * 32 + 16 + q * 4 + r) * 8 + e] = (__bf16)vv;
            }
        }
    }
    __syncthreads();

    // ---- head layer 3 ----
    if (wave < 2) {       // actor logits, cols wave*16 + l16
        f32x4 acc = z4;
        #pragma unroll
        for (int k = 0; k < 8; ++k) {
            const int k8 = k * 4 + q;
            const bf16x8 a0 = *(const bf16x8*)(act2 + (k8 * 32 + l16) * 8);
            const bf16x8 bf = *(const bf16x8*)(AW3f + ((size_t)k8 * 32 + wave * 16 + l16) * 8);
            acc = MFMA(a0, bf, acc);
        }
        const int col = wave * 16 + l16;
        if (col < NOUT_) {
            const float bb = ab3[col];
            #pragma unroll
            for (int r = 0; r < 4; ++r)
                out[(size_t)(b0 + q * 4 + r) * NOUT_ + col] = acc[r] + bb;
        }
    } else if (wave == 2) {  // value
        f32x4 acc = z4;
        #pragma unroll
        for (int k = 0; k < 8; ++k) {
            const int k8 = k * 4 + q;
            const bf16x8 a1 = *(const bf16x8*)(act2 + (k8 * 32 + 16 + l16) * 8);
            const bf16x8 bf = *(const bf16x8*)(VW3f + ((size_t)k8 * 16 + l16) * 8);
            acc = MFMA(a1, bf, acc);
        }
        if (l16 == 0) {
            const float bb = vb3[0];
            #pragma unroll
            for (int r = 0; r < 4; ++r)
                out[(size_t)B_ * NOUT_ + b0 + q * 4 + r] = acc[r] + bb;
        }
    }
}

extern "C" void kernel_launch(void* const* d_in, const int* in_sizes, int n_in,
                              void* d_out, int out_size, void* d_ws, size_t ws_size,
                              hipStream_t stream)
{
    const float* obs = (const float*)d_in[0];
    const float* sW1 = (const float*)d_in[1];
    const float* sb1 = (const float*)d_in[2];
    const float* sW2 = (const float*)d_in[3];
    const float* sb2 = (const float*)d_in[4];
    const float* sW3 = (const float*)d_in[5];
    const float* sb3 = (const float*)d_in[6];
    const float* aW1 = (const float*)d_in[7];
    const float* ab1 = (const float*)d_in[8];
    const float* aW2 = (const float*)d_in[9];
    const float* ab2 = (const float*)d_in[10];
    const float* aW3 = (const float*)d_in[11];
    const float* ab3 = (const float*)d_in[12];
    const float* vW1 = (const float*)d_in[13];
    const float* vb1 = (const float*)d_in[14];
    const float* vW2 = (const float*)d_in[15];
    const float* vb2 = (const float*)d_in[16];
    const float* vW3 = (const float*)d_in[17];
    const float* vb3 = (const float*)d_in[18];

    __bf16* ws = (__bf16*)d_ws;
    float* out = (float*)d_out;

    hipLaunchKernelGGL(prep_kernel, dim3(PREP_TOTAL / 256), dim3(256), 0, stream,
                       sW1, sW2, sW3, aW1, aW2, aW3, vW1, vW2, vW3, ws);
    hipLaunchKernelGGL(fused_kernel, dim3(B_ / 16), dim3(256), 0, stream,
                       obs, sb1, sb2, sb3, ab1, ab2, ab3, vb1, vb2, vb3,
                       (const __bf16*)ws, out);
}

// Round 4
// 281.866 us; speedup vs baseline: 3.1436x; 2.6238x over previous
//
#include <hip/hip_runtime.h>
#include <hip/hip_bf16.h>

#define B_    16384
#define S_    37
#define F_    17
#define OWN_  9
#define NOUT_ 23
#define OBS_ROW 646   // 38*17

typedef __bf16 bf16x8 __attribute__((ext_vector_type(8)));
typedef float  f32x4  __attribute__((ext_vector_type(4)));

#define MFMA(a,b,c) __builtin_amdgcn_mfma_f32_16x16x32_bf16(a, b, c, 0, 0, 0)

// ---- fragment-linear weight layout in ws (bf16 elements) ----
// dst[(k>>3)*(Np*8) + n*8 + (k&7)] = W[k][n]  (zero-padded)
#define W1F_OFF   0        // Np=256, Kp=32   -> 8192
#define W2F_OFF   8192     // Np=256, Kp=256  -> 65536
#define W3F_OFF   73728    // Np=128, Kp=256  -> 32768
#define AW1F_OFF  106496   // Np=256, Kp=160  -> 40960
#define AW2F_OFF  147456   // Np=256, Kp=256  -> 65536
#define AW3F_OFF  212992   // Np=32,  Kp=256  -> 8192
#define VW1F_OFF  221184   // Np=256, Kp=160  -> 40960
#define VW2F_OFF  262144   // Np=256, Kp=256  -> 65536
#define VW3F_OFF  327680   // Np=16,  Kp=256  -> 4096
#define PREP_TOTAL 331776

__global__ void prep_kernel(const float* __restrict__ sW1, const float* __restrict__ sW2,
                            const float* __restrict__ sW3, const float* __restrict__ aW1,
                            const float* __restrict__ aW2, const float* __restrict__ aW3,
                            const float* __restrict__ vW1, const float* __restrict__ vW2,
                            const float* __restrict__ vW3, __bf16* __restrict__ ws)
{
    int j = blockIdx.x * 256 + threadIdx.x;
    const float* src; __bf16* dst; int Np, Ks, Ns;
    if (j < 8192)                  { dst = ws + W1F_OFF;  src = sW1; Np = 256; Ks = 17;  Ns = 256; }
    else if ((j -= 8192)  < 65536) { dst = ws + W2F_OFF;  src = sW2; Np = 256; Ks = 256; Ns = 256; }
    else if ((j -= 65536) < 32768) { dst = ws + W3F_OFF;  src = sW3; Np = 128; Ks = 256; Ns = 128; }
    else if ((j -= 32768) < 40960) { dst = ws + AW1F_OFF; src = aW1; Np = 256; Ks = 137; Ns = 256; }
    else if ((j -= 40960) < 65536) { dst = ws + AW2F_OFF; src = aW2; Np = 256; Ks = 256; Ns = 256; }
    else if ((j -= 65536) < 8192)  { dst = ws + AW3F_OFF; src = aW3; Np = 32;  Ks = 256; Ns = 23;  }
    else if ((j -= 8192)  < 40960) { dst = ws + VW1F_OFF; src = vW1; Np = 256; Ks = 137; Ns = 256; }
    else if ((j -= 40960) < 65536) { dst = ws + VW2F_OFF; src = vW2; Np = 256; Ks = 256; Ns = 256; }
    else { j -= 65536;               dst = ws + VW3F_OFF; src = vW3; Np = 16;  Ks = 256; Ns = 1;   }
    const int c = j / (Np * 8), rem = j - c * Np * 8, n = rem >> 3, e = rem & 7, k = c * 8 + e;
    const float v = (k < Ks && n < Ns) ? src[k * Ns + n] : 0.f;
    dst[j] = (__bf16)v;
}

// 512 threads = 8 waves; block = 16 batch rows; M-tile = 64 rows (16 b x 4 s),
// 10 iters, 3 barriers/iter. Seq-MLP weights (W1/W2/W3 B-frags) live in
// REGISTERS (104 VGPR/thread), loaded once per block -> the K-loop is pure
// ds_read+MFMA, no global streaming (rounds 2/3: spill scratch thrashed L2 and
// weight re-streaming missed to L3 = 1.3GB fetch). launch_bounds(512,2) ->
// 256-reg cap, demand ~200: no spills; 1 block/CU (8 waves).
__global__ __launch_bounds__(512, 2) void fused_kernel(
    const float* __restrict__ obs,
    const float* __restrict__ sb1, const float* __restrict__ sb2, const float* __restrict__ sb3,
    const float* __restrict__ ab1, const float* __restrict__ ab2, const float* __restrict__ ab3,
    const float* __restrict__ vb1, const float* __restrict__ vb2, const float* __restrict__ vb3,
    const __bf16* __restrict__ ws, float* __restrict__ out)
{
    __shared__ __align__(16) char pool[74240];
    __bf16* act1 = (__bf16*)pool;                    // [32 kch][64 row][8]
    __bf16* act2 = (__bf16*)(pool + 32768);          // [32 kch][64 row][8]
    __bf16* xs0  = (__bf16*)(pool + 65536);          // [4 kch][64 row][8]
    __bf16* xs1  = (__bf16*)(pool + 69632);
    float*  sm0  = (float*)(pool + 73728);           // 64 floats
    float*  sm1  = (float*)(pool + 73984);
    __bf16* catf = (__bf16*)(pool + 65536);          // [20 kch][16 row][8] (aliases xs)

    const __bf16* W1f  = ws + W1F_OFF;
    const __bf16* W2f  = ws + W2F_OFF;
    const __bf16* W3f  = ws + W3F_OFF;
    const __bf16* AW1f = ws + AW1F_OFF;
    const __bf16* AW2f = ws + AW2F_OFF;
    const __bf16* AW3f = ws + AW3F_OFF;
    const __bf16* VW1f = ws + VW1F_OFF;
    const __bf16* VW2f = ws + VW2F_OFF;
    const __bf16* VW3f = ws + VW3F_OFF;

    const int tid  = threadIdx.x;
    const int wave = tid >> 6;
    const int lane = tid & 63;
    const int q    = lane >> 4;
    const int l16  = lane & 15;
    const int b0   = blockIdx.x * 16;
    const f32x4 z4 = {0.f, 0.f, 0.f, 0.f};

    // zero both Xs buffers (pad chunks 2,3 stay zero)
    for (int i = tid; i < 4096; i += 512) xs0[i] = (__bf16)0.f;

    // ---- load loop-invariant weights into registers ----
    bf16x8 w1f[2], w2f[8][2], w3f[8];
    float b1v[2], b2v[2];
    #pragma unroll
    for (int nt = 0; nt < 2; ++nt) {
        const int n = wave * 32 + nt * 16 + l16;
        w1f[nt] = *(const bf16x8*)(W1f + ((size_t)q * 256 + n) * 8);
        b1v[nt] = sb1[n];
        b2v[nt] = sb2[n];
        #pragma unroll
        for (int k = 0; k < 8; ++k)
            w2f[k][nt] = *(const bf16x8*)(W2f + ((size_t)(k * 4 + q) * 256 + n) * 8);
    }
    #pragma unroll
    for (int k = 0; k < 8; ++k)
        w3f[k] = *(const bf16x8*)(W3f + ((size_t)(k * 4 + q) * 128 + wave * 16 + l16) * 8);
    const float b3v = sb3[wave * 16 + l16];

    __syncthreads();  // zeros visible before preload stores

    // preload iter 0: rows (b = lane&15, s_local = lane>>4), s = s_local
    if (wave == 7) {
        const float* p = obs + (size_t)(b0 + (lane & 15)) * OBS_ROW + ((lane >> 4) + 1) * F_;
        float sm = 0.f;
        #pragma unroll
        for (int c = 0; c < F_; ++c) {
            const float v = p[c];
            sm += fabsf(v);
            xs0[((c >> 3) * 64 + lane) * 8 + (c & 7)] = (__bf16)v;
        }
        sm0[lane] = sm;
    }

    f32x4 vsum = z4;

    for (int it = 0; it < 10; ++it) {
        __bf16* xc  = (it & 1) ? xs1 : xs0;
        __bf16* xn  = (it & 1) ? xs0 : xs1;
        float*  smc = (it & 1) ? sm1 : sm0;
        float*  smn = (it & 1) ? sm0 : sm1;

        __syncthreads();  // B_a: Xs[cur]/sm[cur] ready; act1,act2 free

        // wave 7: load obs for it+1 into Xs[nxt] (consumed next iter)
        if (it < 9 && wave == 7) {
            const int s = 4 * (it + 1) + (lane >> 4);
            if (s < S_) {
                const float* p = obs + (size_t)(b0 + (lane & 15)) * OBS_ROW + (s + 1) * F_;
                float sm = 0.f;
                #pragma unroll
                for (int c = 0; c < F_; ++c) {
                    const float v = p[c];
                    sm += fabsf(v);
                    xn[((c >> 3) * 64 + lane) * 8 + (c & 7)] = (__bf16)v;
                }
                smn[lane] = sm;
            } else {
                smn[lane] = 0.f;  // stale Xs row masked out
            }
        }

        // ---- layer 1: (64,32) x (32,256) -> act1 ----
        {
            #pragma unroll
            for (int m = 0; m < 4; ++m) {
                const bf16x8 af = *(const bf16x8*)(xc + (q * 64 + m * 16 + l16) * 8);
                #pragma unroll
                for (int nt = 0; nt < 2; ++nt) {
                    const f32x4 h = MFMA(af, w1f[nt], z4);
                    const int n = wave * 32 + nt * 16 + l16, c = n >> 3, e = n & 7;
                    #pragma unroll
                    for (int r = 0; r < 4; ++r) {
                        float v = h[r] + b1v[nt]; v = v > 0.f ? v : 0.f;
                        act1[(c * 64 + m * 16 + q * 4 + r) * 8 + e] = (__bf16)v;
                    }
                }
            }
        }
        __syncthreads();  // B_b: act1 ready

        // ---- layer 2: (64,256) x (256,256) -> act2 ----
        {
            f32x4 h2[2][4];
            #pragma unroll
            for (int nt = 0; nt < 2; ++nt)
                #pragma unroll
                for (int m = 0; m < 4; ++m) h2[nt][m] = z4;
            #pragma unroll
            for (int k = 0; k < 8; ++k) {
                const int k8 = k * 4 + q;
                #pragma unroll
                for (int m = 0; m < 4; ++m) {
                    const bf16x8 a = *(const bf16x8*)(act1 + (k8 * 64 + m * 16 + l16) * 8);
                    h2[0][m] = MFMA(a, w2f[k][0], h2[0][m]);
                    h2[1][m] = MFMA(a, w2f[k][1], h2[1][m]);
                }
            }
            #pragma unroll
            for (int nt = 0; nt < 2; ++nt) {
                const int n = wave * 32 + nt * 16 + l16, c = n >> 3, e = n & 7;
                #pragma unroll
                for (int m = 0; m < 4; ++m)
                    #pragma unroll
                    for (int r = 0; r < 4; ++r) {
                        float v = h2[nt][m][r] + b2v[nt]; v = v > 0.f ? v : 0.f;
                        act2[(c * 64 + m * 16 + q * 4 + r) * 8 + e] = (__bf16)v;
                    }
            }
        }
        __syncthreads();  // B_c: act2 ready

        // ---- layer 3: (64,256) x (256,128), relu, mask, pool over s ----
        {
            f32x4 h3[4];
            #pragma unroll
            for (int m = 0; m < 4; ++m) h3[m] = z4;
            #pragma unroll
            for (int k = 0; k < 8; ++k) {
                const int k8 = k * 4 + q;
                #pragma unroll
                for (int m = 0; m < 4; ++m) {
                    const bf16x8 a = *(const bf16x8*)(act2 + (k8 * 64 + m * 16 + l16) * 8);
                    h3[m] = MFMA(a, w3f[k], h3[m]);
                }
            }
            #pragma unroll
            for (int m = 0; m < 4; ++m)
                #pragma unroll
                for (int r = 0; r < 4; ++r) {
                    const float mv = smc[m * 16 + q * 4 + r];
                    float v = h3[m][r] + b3v;
                    v = v > 0.f ? v : 0.f;
                    vsum[r] += (mv != 0.f) ? v : 0.f;
                }
    }
    }

    __syncthreads();  // seq loop done; xs/sm dead -> catf writable

    // ---- stage cat (frag-major, 16 rows x 20 chunks) ----
    if (tid < 16) {
        const float* p = obs + (size_t)(b0 + tid) * OBS_ROW;  // s_own
        #pragma unroll
        for (int c = 0; c < 8; ++c) catf[(16 * 16 + tid) * 8 + c] = (__bf16)p[c];
        catf[(17 * 16 + tid) * 8 + 0] = (__bf16)p[8];
        #pragma unroll
        for (int c = 1; c < 8; ++c) catf[(17 * 16 + tid) * 8 + c] = (__bf16)0.f;
    } else if (tid < 32) {
        const int rr = tid - 16;
        #pragma unroll
        for (int c = 0; c < 8; ++c) {
            catf[(18 * 16 + rr) * 8 + c] = (__bf16)0.f;
            catf[(19 * 16 + rr) * 8 + c] = (__bf16)0.f;
        }
    }
    {
        const int col = wave * 16 + l16, c = col >> 3, e = col & 7;
        #pragma unroll
        for (int r = 0; r < 4; ++r)
            catf[(c * 16 + q * 4 + r) * 8 + e] = (__bf16)vsum[r];
    }
    __syncthreads();  // catf ready

    // ---- head layer 1: (16,160) x (160,256), both heads -> act1 ----
    {
        f32x4 ha[2], hv[2];
        #pragma unroll
        for (int nt = 0; nt < 2; ++nt) { ha[nt] = z4; hv[nt] = z4; }
        #pragma unroll
        for (int k = 0; k < 5; ++k) {
            const int k8 = k * 4 + q;
            const bf16x8 ca = *(const bf16x8*)(catf + (k8 * 16 + l16) * 8);
            #pragma unroll
            for (int nt = 0; nt < 2; ++nt) {
                const int n = wave * 32 + nt * 16 + l16;
                const bf16x8 ba = *(const bf16x8*)(AW1f + ((size_t)k8 * 256 + n) * 8);
                const bf16x8 bv = *(const bf16x8*)(VW1f + ((size_t)k8 * 256 + n) * 8);
                ha[nt] = MFMA(ca, ba, ha[nt]);
                hv[nt] = MFMA(ca, bv, hv[nt]);
            }
        }
        #pragma unroll
        for (int nt = 0; nt < 2; ++nt) {
            const int n = wave * 32 + nt * 16 + l16, c = n >> 3, e = n & 7;
            const float ba_ = ab1[n], bv_ = vb1[n];
            #pragma unroll
            for (int r = 0; r < 4; ++r) {
                float va = ha[nt][r] + ba_; va = va > 0.f ? va : 0.f;
                float vv = hv[nt][r] + bv_; vv = vv > 0.f ? vv : 0.f;
                act1[(c * 64 + q * 4 + r) * 8 + e]      = (__bf16)va;   // actor rows 0..15
                act1[(c * 64 + 16 + q * 4 + r) * 8 + e] = (__bf16)vv;   // value rows 16..31
            }
        }
    }
    __syncthreads();

    // ---- head layer 2: (16,256) x (256,256), both heads -> act2 ----
    {
        f32x4 ha[2], hv[2];
        #pragma unroll
        for (int nt = 0; nt < 2; ++nt) { ha[nt] = z4; hv[nt] = z4; }
        #pragma unroll
        for (int k = 0; k < 8; ++k) {
            const int k8 = k * 4 + q;
            const bf16x8 a0 = *(const bf16x8*)(act1 + (k8 * 64 + l16) * 8);
            const bf16x8 a1 = *(const bf16x8*)(act1 + (k8 * 64 + 16 + l16) * 8);
            #pragma unroll
            for (int nt = 0; nt < 2; ++nt) {
                const int n = wave * 32 + nt * 16 + l16;
                const bf16x8 ba = *(const bf16x8*)(AW2f + ((size_t)k8 * 256 + n) * 8);
                const bf16x8 bv = *(const bf16x8*)(VW2f + ((size_t)k8 * 256 + n) * 8);
                ha[nt] = MFMA(a0, ba, ha[nt]);
                hv[nt] = MFMA(a1, bv, hv[nt]);
            }
        }
        #pragma unroll
        for (int nt = 0; nt < 2; ++nt) {
            const int n = wave * 32 + nt * 16 + l16, c = n >> 3, e = n & 7;
            const float ba_ = ab2[n], bv_ = vb2[n];
            #pragma unroll
            for (int r = 0; r < 4; ++r) {
                float va = ha[nt][r] + ba_; va = va > 0.f ? va : 0.f;
                float vv = hv[nt][r] + bv_; vv = vv > 0.f ? vv : 0.f;
                act2[(c * 64 + q * 4 + r) * 8 + e]      = (__bf16)va;
                act2[(c * 64 + 16 + q * 4 + r) * 8 + e] = (__bf16)vv;
            }
        }
    }
    __syncthreads();

    // ---- head layer 3 ----
    if (wave < 2) {       // actor logits, cols wave*16 + l16
        f32x4 acc = z4;
        #pragma unroll
        for (int k = 0; k < 8; ++k) {
            const int k8 = k * 4 + q;
            const bf16x8 a0 = *(const bf16x8*)(act2 + (k8 * 64 + l16) * 8);
            const bf16x8 bf = *(const bf16x8*)(AW3f + ((size_t)k8 * 32 + wave * 16 + l16) * 8);
            acc = MFMA(a0, bf, acc);
        }
        const int col = wave * 16 + l16;
        if (col < NOUT_) {
            const float bb = ab3[col];
            #pragma unroll
            for (int r = 0; r < 4; ++r)
                out[(size_t)(b0 + q * 4 + r) * NOUT_ + col] = acc[r] + bb;
        }
    } else if (wave == 2) {  // value
        f32x4 acc = z4;
        #pragma unroll
        for (int k = 0; k < 8; ++k) {
            const int k8 = k * 4 + q;
            const bf16x8 a1 = *(const bf16x8*)(act2 + (k8 * 64 + 16 + l16) * 8);
            const bf16x8 bf = *(const bf16x8*)(VW3f + ((size_t)k8 * 16 + l16) * 8);
            acc = MFMA(a1, bf, acc);
        }
        if (l16 == 0) {
            const float bb = vb3[0];
            #pragma unroll
            for (int r = 0; r < 4; ++r)
                out[(size_t)B_ * NOUT_ + b0 + q * 4 + r] = acc[r] + bb;
        }
    }
}

extern "C" void kernel_launch(void* const* d_in, const int* in_sizes, int n_in,
                              void* d_out, int out_size, void* d_ws, size_t ws_size,
                              hipStream_t stream)
{
    const float* obs = (const float*)d_in[0];
    const float* sW1 = (const float*)d_in[1];
    const float* sb1 = (const float*)d_in[2];
    const float* sW2 = (const float*)d_in[3];
    const float* sb2 = (const float*)d_in[4];
    const float* sW3 = (const float*)d_in[5];
    const float* sb3 = (const float*)d_in[6];
    const float* aW1 = (const float*)d_in[7];
    const float* ab1 = (const float*)d_in[8];
    const float* aW2 = (const float*)d_in[9];
    const float* ab2 = (const float*)d_in[10];
    const float* aW3 = (const float*)d_in[11];
    const float* ab3 = (const float*)d_in[12];
    const float* vW1 = (const float*)d_in[13];
    const float* vb1 = (const float*)d_in[14];
    const float* vW2 = (const float*)d_in[15];
    const float* vb2 = (const float*)d_in[16];
    const float* vW3 = (const float*)d_in[17];
    const float* vb3 = (const float*)d_in[18];

    __bf16* ws = (__bf16*)d_ws;
    float* out = (float*)d_out;

    hipLaunchKernelGGL(prep_kernel, dim3(PREP_TOTAL / 256), dim3(256), 0, stream,
                       sW1, sW2, sW3, aW1, aW2, aW3, vW1, vW2, vW3, ws);
    hipLaunchKernelGGL(fused_kernel, dim3(B_ / 16), dim3(512), 0, stream,
                       obs, sb1, sb2, sb3, ab1, ab2, ab3, vb1, vb2, vb3,
                       (const __bf16*)ws, out);
}